// Round 14
// baseline (275.475 us; speedup 1.0000x reference)
//
#include <hip/hip_runtime.h>
#include <hip/hip_bf16.h>

typedef __bf16 bf16_t;
typedef __bf16 bf16x8 __attribute__((ext_vector_type(8)));
typedef float  f32x4  __attribute__((ext_vector_type(4)));
typedef float  f32x4v __attribute__((ext_vector_type(4)));   // for nt load/store

#define DM    512
#define NQKV  1536
#define NTOK  65536
#define TM    32          // tokens per block
#define EXSTR 1544        // exchange LDS row stride (elems): 1536 + 8 pad

// Fragment-major repacked weights, head-pair mapping for 4-wave blocks:
// for wave w (0..3), K-step s (0..15), quarter nq (0..3), ni (0..5),
// lane l (0..63), elem e (0..7):
//   ELEM offset = ((((w*16+s)*4+nq)*6+ni)*64 + l)*8 + e
//   gni = nq*6+ni (0..23); part = gni>>3 (0=q,1=k,2=v); within = gni&7
//   n = part*512 + w*128 + within*16 + (l&15);  k = s*32 + (l>>4)*8 + e
// Wave w's 24-frag N-slice = q,k,v of heads {2w, 2w+1}.
// Per-wave slice = 196608 elems; quarter-step = 3072 elems; frag = 512 elems.
__device__ __align__(16) bf16_t g_wt2[(size_t)NQKV * DM];

#define MEMFENCE asm volatile("" ::: "memory")

typedef const void __attribute__((address_space(1)))* gas_t;
typedef void       __attribute__((address_space(3)))* sas_t;
__device__ __forceinline__ void gl_lds16(const void* g, void* s) {
    // async global->LDS, 16B/lane; LDS dest = wave-uniform base + lane*16
    __builtin_amdgcn_global_load_lds((gas_t)g, (sas_t)s, 16, 0, 0);
}

// ---------------------------------------------------------------------------
// Kernel 1: scatter W_q|W_k|W_v (fp32 [k][n]) -> g_wt2 (head-pair mapping)
// ---------------------------------------------------------------------------
__global__ void prep_w2(const float* __restrict__ Wq,
                        const float* __restrict__ Wk,
                        const float* __restrict__ Wv) {
    int flat = blockIdx.x * 256 + threadIdx.x;   // 0..98303 (one bf16x8 each)
    int l   = flat & 63;
    int u   = flat >> 6;                          // 0..1535
    int ni6 = u % 6;
    int u2  = u / 6;
    int nq  = u2 & 3;
    int u3  = u2 >> 2;
    int s   = u3 & 15, w = u3 >> 4;               // w 0..3
    int gni = nq * 6 + ni6;
    int part = gni >> 3, within = gni & 7;
    int n   = part * 512 + w * 128 + within * 16 + (l & 15);   // 0..1535
    int k0  = s * 32 + (l >> 4) * 8;
    int mat = n >> 9, nn = n & 511;
    const float* W = (mat == 0) ? Wq : ((mat == 1) ? Wk : Wv);
    bf16x8 v;
#pragma unroll
    for (int e = 0; e < 8; ++e) v[e] = (bf16_t)W[(k0 + e) * DM + nn];
    *(bf16x8*)(g_wt2 + (size_t)flat * 8) = v;
}

// ---------------------------------------------------------------------------
// Kernel 2: fused QKV projection + cross-head attention, 2-blocks/CU layout.
// 256 threads (4 waves), 32 tokens/block, 2048 blocks.
// R14 = R13 + NON-TEMPORAL x loads / out stores: keeps the once-touched
// x/out streams out of L2 so the 1.5 MB weight set stays resident (R13's
// FETCH_SIZE +45 MB showed the streams evicting it at 2 blocks/CU).
// LDS (81920 B -> two blocks co-resident per CU):
//   [0,32K) A tile | [32K,80K) B ring (4 waves x 2 x 6144 B)
//   after K-loop: exchange ex[16][EXSTR] bf16 overlays from 0
// ---------------------------------------------------------------------------
__global__ __launch_bounds__(256, 2) void fused_mha(
    const float* __restrict__ x, float* __restrict__ out) {
    extern __shared__ char sm[];        // 81920 B

    const int tid = threadIdx.x;
    const int l   = tid & 63, w = tid >> 6;       // lane, wave 0..3
    const int lr  = l & 15,  kg = l >> 4;
    const size_t tok0 = (size_t)blockIdx.x * TM;

    // ---- stage x tile: fp32 global (nt) -> bf16 LDS, 16B-chunk XOR swizzle -
#pragma unroll
    for (int p = 0; p < 8; ++p) {
        int flat = p * 256 + tid;                 // 0..2047
        int r = flat >> 6, c = flat & 63;
        const f32x4v* xp = (const f32x4v*)(x + (tok0 + r) * DM + c * 8);
        f32x4v f0 = __builtin_nontemporal_load(xp);
        f32x4v f1 = __builtin_nontemporal_load(xp + 1);
        bf16x8 v;
        v[0] = (bf16_t)f0.x; v[1] = (bf16_t)f0.y;
        v[2] = (bf16_t)f0.z; v[3] = (bf16_t)f0.w;
        v[4] = (bf16_t)f1.x; v[5] = (bf16_t)f1.y;
        v[6] = (bf16_t)f1.z; v[7] = (bf16_t)f1.w;
        *(bf16x8*)(sm + r * 1024 + ((c ^ (r & 7)) << 4)) = v;
    }

    // ---- B ring: 2 slots x 6144 B per wave at sm+32768 --------------------
    // Per-lane source (ELEMENT offsets: wave slice 196608, quarter 3072).
    const bf16_t* gwB = g_wt2 + (size_t)w * 196608 + l * 8;
    char* ringW = sm + 32768 + w * 12288;                      // wave-uniform

#define ISSUE6(h_)                                                            \
    do {                                                                      \
        _Pragma("unroll")                                                     \
        for (int ii = 0; ii < 6; ++ii)                                        \
            gl_lds16(gwB + (size_t)(h_) * 3072 + ii * 512,                    \
                     ringW + ((h_) & 1) * 6144 + ii * 1024);                  \
    } while (0)
#define WAITVM(n_) asm volatile("s_waitcnt vmcnt(" #n_ ")" ::: "memory")

    // prologue: quarter-steps 0,1 in flight before the staging barrier
    ISSUE6(0); ISSUE6(1);
    asm volatile("s_waitcnt lgkmcnt(0)" ::: "memory");  // x ds_writes drained
    __builtin_amdgcn_s_barrier();
    MEMFENCE;

    // ---- barrier-free K-loop: 64 quarter-steps, fully unrolled -------------
    f32x4 acc[2][24];
#pragma unroll
    for (int a = 0; a < 2; ++a)
#pragma unroll
        for (int b = 0; b < 24; ++b) acc[a][b] = (f32x4){0.f, 0.f, 0.f, 0.f};

    const int sx = (lr & 7) << 4;               // A-read swizzle term
    bf16x8 af[2];

#define HSTEP(h_, vm_)                                                        \
    do {                                                                      \
        WAITVM(vm_);              /* slot h_'s 6 stage-loads retired */       \
        bf16x8 bf_[6];                                                        \
        _Pragma("unroll")                                                     \
        for (int ni = 0; ni < 6; ++ni)                                        \
            bf_[ni] = *(const bf16x8*)(ringW + ((h_) & 1) * 6144 +            \
                                       ni * 1024 + l * 16);                   \
        if (((h_) & 3) == 0) {                                                \
            _Pragma("unroll")                                                 \
            for (int mi = 0; mi < 2; ++mi)                                    \
                af[mi] = *(const bf16x8*)(sm + (mi * 16 + lr) * 1024 +        \
                                          ((((h_) >> 2) * 64 + kg * 16) ^ sx)); \
        }                                                                     \
        asm volatile("s_waitcnt lgkmcnt(0)" ::: "memory");                    \
        __builtin_amdgcn_sched_barrier(0);      /* rule #18 */                \
        if ((h_) + 2 < 64) ISSUE6((h_) + 2);    /* refill freed slot */       \
        __builtin_amdgcn_s_setprio(1);                                        \
        _Pragma("unroll")                                                     \
        for (int mi = 0; mi < 2; ++mi)                                        \
        _Pragma("unroll")                                                     \
        for (int ni = 0; ni < 6; ++ni)                                        \
            acc[mi][((h_) & 3) * 6 + ni] =                                    \
                __builtin_amdgcn_mfma_f32_16x16x32_bf16(                      \
                    af[mi], bf_[ni], acc[mi][((h_) & 3) * 6 + ni], 0, 0, 0);  \
        __builtin_amdgcn_s_setprio(0);                                        \
    } while (0)

    HSTEP( 0, 6); HSTEP( 1, 6); HSTEP( 2, 6); HSTEP( 3, 6);
    HSTEP( 4, 6); HSTEP( 5, 6); HSTEP( 6, 6); HSTEP( 7, 6);
    HSTEP( 8, 6); HSTEP( 9, 6); HSTEP(10, 6); HSTEP(11, 6);
    HSTEP(12, 6); HSTEP(13, 6); HSTEP(14, 6); HSTEP(15, 6);
    HSTEP(16, 6); HSTEP(17, 6); HSTEP(18, 6); HSTEP(19, 6);
    HSTEP(20, 6); HSTEP(21, 6); HSTEP(22, 6); HSTEP(23, 6);
    HSTEP(24, 6); HSTEP(25, 6); HSTEP(26, 6); HSTEP(27, 6);
    HSTEP(28, 6); HSTEP(29, 6); HSTEP(30, 6); HSTEP(31, 6);
    HSTEP(32, 6); HSTEP(33, 6); HSTEP(34, 6); HSTEP(35, 6);
    HSTEP(36, 6); HSTEP(37, 6); HSTEP(38, 6); HSTEP(39, 6);
    HSTEP(40, 6); HSTEP(41, 6); HSTEP(42, 6); HSTEP(43, 6);
    HSTEP(44, 6); HSTEP(45, 6); HSTEP(46, 6); HSTEP(47, 6);
    HSTEP(48, 6); HSTEP(49, 6); HSTEP(50, 6); HSTEP(51, 6);
    HSTEP(52, 6); HSTEP(53, 6); HSTEP(54, 6); HSTEP(55, 6);
    HSTEP(56, 6); HSTEP(57, 6); HSTEP(58, 6); HSTEP(59, 6);
    HSTEP(60, 6); HSTEP(61, 6); HSTEP(62, 6); HSTEP(63, 0);
#undef HSTEP
#undef ISSUE6
#undef WAITVM

    // ---- A + ring dead; full drain + sync before exchange overlays ---------
    asm volatile("s_waitcnt vmcnt(0) lgkmcnt(0)" ::: "memory");
    __builtin_amdgcn_s_barrier();
    MEMFENCE;

    // ---- two passes: exchange 16 tokens -> LDS, then attention -------------
    bf16_t* ex = (bf16_t*)sm;
#pragma unroll
    for (int mi = 0; mi < 2; ++mi) {
        // exchange: acc[mi] -> ex[16][EXSTR]  (row = token-in-pass, col = n)
#pragma unroll
        for (int gni = 0; gni < 24; ++gni) {
            int col = (gni >> 3) * 512 + w * 128 + (gni & 7) * 16 + lr;
#pragma unroll
            for (int i = 0; i < 4; ++i) {
                int tl = kg * 4 + i;              // 0..15
                ex[tl * EXSTR + col] = (bf16_t)acc[mi][gni][i];
            }
        }
        asm volatile("s_waitcnt lgkmcnt(0)" ::: "memory");
        __builtin_amdgcn_s_barrier();
        MEMFENCE;

        // attention: 16 threads per token, 16 tokens (= 256 threads exactly)
        {
            const int tl = tid >> 4, tj = tid & 15, h = tj & 7, d0 = (tj >> 3) << 5;
            const bf16_t* base = ex + tl * EXSTR;

            float qv[32];
            {
                const bf16_t* qp = base + h * 64 + d0;
#pragma unroll
                for (int j = 0; j < 4; ++j) {
                    bf16x8 q8 = *(const bf16x8*)(qp + 8 * j);
#pragma unroll
                    for (int e = 0; e < 8; ++e) qv[8 * j + e] = (float)q8[e];
                }
            }

            float s[8];
#pragma unroll
            for (int t = 0; t < 8; ++t) {
                const bf16_t* kp = base + 512 + t * 64 + d0;
                float a = 0.f;
#pragma unroll
                for (int j = 0; j < 4; ++j) {
                    bf16x8 k8 = *(const bf16x8*)(kp + 8 * j);
#pragma unroll
                    for (int e = 0; e < 8; ++e) a += qv[8 * j + e] * (float)k8[e];
                }
                s[t] = a;
            }
            // combine two d-halves (partner lane tid^8: same token, same h)
#pragma unroll
            for (int t = 0; t < 8; ++t) s[t] += __shfl_xor(s[t], 8, 64);

            float m = s[0];
#pragma unroll
            for (int t = 1; t < 8; ++t) m = fmaxf(m, s[t]);
            float pr[8], psum = 0.f;
#pragma unroll
            for (int t = 0; t < 8; ++t) {
                pr[t] = exp2f((s[t] - m) * 1.44269504088896f);
                psum += pr[t];
            }
            float inv = 1.0f / psum;

            float o[32];
#pragma unroll
            for (int e = 0; e < 32; ++e) o[e] = 0.f;
#pragma unroll
            for (int t = 0; t < 8; ++t) {
                float pt = pr[t] * inv;
                const bf16_t* vp = base + 1024 + t * 64 + d0;
#pragma unroll
                for (int j = 0; j < 4; ++j) {
                    bf16x8 v8 = *(const bf16x8*)(vp + 8 * j);
#pragma unroll
                    for (int e = 0; e < 8; ++e) o[8 * j + e] += pt * (float)v8[e];
                }
            }

            float* op = out + (tok0 + mi * 16 + tl) * DM + h * 64 + d0;
#pragma unroll
            for (int j = 0; j < 8; ++j) {
                f32x4v o4 = {o[4 * j], o[4 * j + 1], o[4 * j + 2], o[4 * j + 3]};
                __builtin_nontemporal_store(o4, (f32x4v*)(op + 4 * j));
            }
        }
        if (mi == 0) {                 // ex reads done before pass-2 overwrite
            __builtin_amdgcn_s_barrier();
            MEMFENCE;
        }
    }
}

// ---------------------------------------------------------------------------
extern "C" void kernel_launch(void* const* d_in, const int* in_sizes, int n_in,
                              void* d_out, int out_size, void* d_ws, size_t ws_size,
                              hipStream_t stream) {
    (void)d_ws; (void)ws_size; (void)n_in; (void)out_size;
    const float* x  = (const float*)d_in[0];
    const float* Wq = (const float*)d_in[1];
    const float* Wk = (const float*)d_in[2];
    const float* Wv = (const float*)d_in[3];
    float* out = (float*)d_out;

    int ntok = in_sizes[0] / DM;                  // 65536
    prep_w2<<<384, 256, 0, stream>>>(Wq, Wk, Wv);
    size_t lds = 81920;                           // A 32K + ring 48K (2 blk/CU)
    fused_mha<<<ntok / TM, 256, lds, stream>>>(x, out);
}

// Round 15
// 226.888 us; speedup vs baseline: 1.2141x; 1.2141x over previous
//
#include <hip/hip_runtime.h>
#include <hip/hip_bf16.h>

typedef __bf16 bf16_t;
typedef __bf16 bf16x8 __attribute__((ext_vector_type(8)));
typedef float  f32x4  __attribute__((ext_vector_type(4)));

#define DM    512
#define NQKV  1536
#define NTOK  65536
#define TM    32          // tokens per block
#define EXSTR 1544        // exchange LDS row stride (elems): 1536 + 8 pad
#define OSTR  520         // fp32 out-buffer row stride (floats): 512 + 8

// Fragment-major repacked weights, head-pair mapping for 4-wave blocks:
// for wave w (0..3), K-step s (0..15), quarter nq (0..3), ni (0..5),
// lane l (0..63), elem e (0..7):
//   ELEM offset = ((((w*16+s)*4+nq)*6+ni)*64 + l)*8 + e
//   gni = nq*6+ni (0..23); part = gni>>3 (0=q,1=k,2=v); within = gni&7
//   n = part*512 + w*128 + within*16 + (l&15);  k = s*32 + (l>>4)*8 + e
// Per-wave slice = 196608 elems; quarter-step = 3072 elems; frag = 512 elems.
__device__ __align__(16) bf16_t g_wt2[(size_t)NQKV * DM];

#define MEMFENCE asm volatile("" ::: "memory")

typedef const void __attribute__((address_space(1)))* gas_t;
typedef void       __attribute__((address_space(3)))* sas_t;
__device__ __forceinline__ void gl_lds16(const void* g, void* s) {
    // async global->LDS, 16B/lane; LDS dest = wave-uniform base + lane*16
    __builtin_amdgcn_global_load_lds((gas_t)g, (sas_t)s, 16, 0, 0);
}

// ---------------------------------------------------------------------------
// Kernel 1: scatter W_q|W_k|W_v (fp32 [k][n]) -> g_wt2 (head-pair mapping)
// ---------------------------------------------------------------------------
__global__ void prep_w2(const float* __restrict__ Wq,
                        const float* __restrict__ Wk,
                        const float* __restrict__ Wv) {
    int flat = blockIdx.x * 256 + threadIdx.x;   // 0..98303 (one bf16x8 each)
    int l   = flat & 63;
    int u   = flat >> 6;                          // 0..1535
    int ni6 = u % 6;
    int u2  = u / 6;
    int nq  = u2 & 3;
    int u3  = u2 >> 2;
    int s   = u3 & 15, w = u3 >> 4;               // w 0..3
    int gni = nq * 6 + ni6;
    int part = gni >> 3, within = gni & 7;
    int n   = part * 512 + w * 128 + within * 16 + (l & 15);   // 0..1535
    int k0  = s * 32 + (l >> 4) * 8;
    int mat = n >> 9, nn = n & 511;
    const float* W = (mat == 0) ? Wq : ((mat == 1) ? Wk : Wv);
    bf16x8 v;
#pragma unroll
    for (int e = 0; e < 8; ++e) v[e] = (bf16_t)W[(k0 + e) * DM + nn];
    *(bf16x8*)(g_wt2 + (size_t)flat * 8) = v;
}

// ---------------------------------------------------------------------------
// Kernel 2: fused QKV projection + cross-head attention, 2-blocks/CU layout.
// 256 threads (4 waves), 32 tokens/block, 2048 blocks.
// R15 = R13 + nt x-loads (keeps weights L2-resident; R14-verified FETCH
// 148->106 MB) + full-line out writes: o -> LDS fp32 [16][OSTR] -> lane-
// contiguous nt store copy (1 KB contiguous per wave instr = 16 complete
// 64B lines -> no partial-line RMW amplification, zero L2 footprint).
// R14's direct nt stores were 16B scattered granules -> 485 MB (4x) writes.
// LDS (81920 B -> two blocks co-resident per CU):
//   [0,32K) A tile | [32K,80K) B ring (4 waves x 2 x 6144 B)
//   attention phase: ex[16][EXSTR] bf16 then ob[16][OSTR] f32 overlay from 0
// ---------------------------------------------------------------------------
__global__ __launch_bounds__(256, 2) void fused_mha(
    const float* __restrict__ x, float* __restrict__ out) {
    extern __shared__ char sm[];        // 81920 B

    const int tid = threadIdx.x;
    const int l   = tid & 63, w = tid >> 6;       // lane, wave 0..3
    const int lr  = l & 15,  kg = l >> 4;
    const size_t tok0 = (size_t)blockIdx.x * TM;

    // ---- stage x tile: fp32 global (nt) -> bf16 LDS, 16B-chunk XOR swizzle -
#pragma unroll
    for (int p = 0; p < 8; ++p) {
        int flat = p * 256 + tid;                 // 0..2047
        int r = flat >> 6, c = flat & 63;
        const f32x4* xp = (const f32x4*)(x + (tok0 + r) * DM + c * 8);
        f32x4 f0 = __builtin_nontemporal_load(xp);
        f32x4 f1 = __builtin_nontemporal_load(xp + 1);
        bf16x8 v;
        v[0] = (bf16_t)f0.x; v[1] = (bf16_t)f0.y;
        v[2] = (bf16_t)f0.z; v[3] = (bf16_t)f0.w;
        v[4] = (bf16_t)f1.x; v[5] = (bf16_t)f1.y;
        v[6] = (bf16_t)f1.z; v[7] = (bf16_t)f1.w;
        *(bf16x8*)(sm + r * 1024 + ((c ^ (r & 7)) << 4)) = v;
    }

    // ---- B ring: 2 slots x 6144 B per wave at sm+32768 --------------------
    const bf16_t* gwB = g_wt2 + (size_t)w * 196608 + l * 8;   // elem offsets
    char* ringW = sm + 32768 + w * 12288;                      // wave-uniform

#define ISSUE6(h_)                                                            \
    do {                                                                      \
        _Pragma("unroll")                                                     \
        for (int ii = 0; ii < 6; ++ii)                                        \
            gl_lds16(gwB + (size_t)(h_) * 3072 + ii * 512,                    \
                     ringW + ((h_) & 1) * 6144 + ii * 1024);                  \
    } while (0)
#define WAITVM(n_) asm volatile("s_waitcnt vmcnt(" #n_ ")" ::: "memory")

    // prologue: quarter-steps 0,1 in flight before the staging barrier
    ISSUE6(0); ISSUE6(1);
    asm volatile("s_waitcnt lgkmcnt(0)" ::: "memory");  // x ds_writes drained
    __builtin_amdgcn_s_barrier();
    MEMFENCE;

    // ---- barrier-free K-loop: 64 quarter-steps, fully unrolled -------------
    f32x4 acc[2][24];
#pragma unroll
    for (int a = 0; a < 2; ++a)
#pragma unroll
        for (int b = 0; b < 24; ++b) acc[a][b] = (f32x4){0.f, 0.f, 0.f, 0.f};

    const int sx = (lr & 7) << 4;               // A-read swizzle term
    bf16x8 af[2];

#define HSTEP(h_, vm_)                                                        \
    do {                                                                      \
        WAITVM(vm_);              /* slot h_'s 6 stage-loads retired */       \
        bf16x8 bf_[6];                                                        \
        _Pragma("unroll")                                                     \
        for (int ni = 0; ni < 6; ++ni)                                        \
            bf_[ni] = *(const bf16x8*)(ringW + ((h_) & 1) * 6144 +            \
                                       ni * 1024 + l * 16);                   \
        if (((h_) & 3) == 0) {                                                \
            _Pragma("unroll")                                                 \
            for (int mi = 0; mi < 2; ++mi)                                    \
                af[mi] = *(const bf16x8*)(sm + (mi * 16 + lr) * 1024 +        \
                                          ((((h_) >> 2) * 64 + kg * 16) ^ sx)); \
        }                                                                     \
        asm volatile("s_waitcnt lgkmcnt(0)" ::: "memory");                    \
        __builtin_amdgcn_sched_barrier(0);      /* rule #18 */                \
        if ((h_) + 2 < 64) ISSUE6((h_) + 2);    /* refill freed slot */       \
        __builtin_amdgcn_s_setprio(1);                                        \
        _Pragma("unroll")                                                     \
        for (int mi = 0; mi < 2; ++mi)                                        \
        _Pragma("unroll")                                                     \
        for (int ni = 0; ni < 6; ++ni)                                        \
            acc[mi][((h_) & 3) * 6 + ni] =                                    \
                __builtin_amdgcn_mfma_f32_16x16x32_bf16(                      \
                    af[mi], bf_[ni], acc[mi][((h_) & 3) * 6 + ni], 0, 0, 0);  \
        __builtin_amdgcn_s_setprio(0);                                        \
    } while (0)

    HSTEP( 0, 6); HSTEP( 1, 6); HSTEP( 2, 6); HSTEP( 3, 6);
    HSTEP( 4, 6); HSTEP( 5, 6); HSTEP( 6, 6); HSTEP( 7, 6);
    HSTEP( 8, 6); HSTEP( 9, 6); HSTEP(10, 6); HSTEP(11, 6);
    HSTEP(12, 6); HSTEP(13, 6); HSTEP(14, 6); HSTEP(15, 6);
    HSTEP(16, 6); HSTEP(17, 6); HSTEP(18, 6); HSTEP(19, 6);
    HSTEP(20, 6); HSTEP(21, 6); HSTEP(22, 6); HSTEP(23, 6);
    HSTEP(24, 6); HSTEP(25, 6); HSTEP(26, 6); HSTEP(27, 6);
    HSTEP(28, 6); HSTEP(29, 6); HSTEP(30, 6); HSTEP(31, 6);
    HSTEP(32, 6); HSTEP(33, 6); HSTEP(34, 6); HSTEP(35, 6);
    HSTEP(36, 6); HSTEP(37, 6); HSTEP(38, 6); HSTEP(39, 6);
    HSTEP(40, 6); HSTEP(41, 6); HSTEP(42, 6); HSTEP(43, 6);
    HSTEP(44, 6); HSTEP(45, 6); HSTEP(46, 6); HSTEP(47, 6);
    HSTEP(48, 6); HSTEP(49, 6); HSTEP(50, 6); HSTEP(51, 6);
    HSTEP(52, 6); HSTEP(53, 6); HSTEP(54, 6); HSTEP(55, 6);
    HSTEP(56, 6); HSTEP(57, 6); HSTEP(58, 6); HSTEP(59, 6);
    HSTEP(60, 6); HSTEP(61, 6); HSTEP(62, 6); HSTEP(63, 0);
#undef HSTEP
#undef ISSUE6
#undef WAITVM

    // ---- A + ring dead; full drain + sync before exchange overlays ---------
    asm volatile("s_waitcnt vmcnt(0) lgkmcnt(0)" ::: "memory");
    __builtin_amdgcn_s_barrier();
    MEMFENCE;

    // ---- two passes: exchange 16 tokens -> attention -> full-line out ------
    bf16_t* ex = (bf16_t*)sm;
    float*  ob = (float*)sm;
#pragma unroll
    for (int mi = 0; mi < 2; ++mi) {
        // exchange: acc[mi] -> ex[16][EXSTR]  (row = token-in-pass, col = n)
#pragma unroll
        for (int gni = 0; gni < 24; ++gni) {
            int col = (gni >> 3) * 512 + w * 128 + (gni & 7) * 16 + lr;
#pragma unroll
            for (int i = 0; i < 4; ++i) {
                int tl = kg * 4 + i;              // 0..15
                ex[tl * EXSTR + col] = (bf16_t)acc[mi][gni][i];
            }
        }
        asm volatile("s_waitcnt lgkmcnt(0)" ::: "memory");
        __builtin_amdgcn_s_barrier();
        MEMFENCE;

        // attention: 16 threads per token, 16 tokens (= 256 threads exactly)
        {
            const int tl = tid >> 4, tj = tid & 15, h = tj & 7, d0 = (tj >> 3) << 5;
            const bf16_t* base = ex + tl * EXSTR;

            float qv[32];
            {
                const bf16_t* qp = base + h * 64 + d0;
#pragma unroll
                for (int j = 0; j < 4; ++j) {
                    bf16x8 q8 = *(const bf16x8*)(qp + 8 * j);
#pragma unroll
                    for (int e = 0; e < 8; ++e) qv[8 * j + e] = (float)q8[e];
                }
            }

            float s[8];
#pragma unroll
            for (int t = 0; t < 8; ++t) {
                const bf16_t* kp = base + 512 + t * 64 + d0;
                float a = 0.f;
#pragma unroll
                for (int j = 0; j < 4; ++j) {
                    bf16x8 k8 = *(const bf16x8*)(kp + 8 * j);
#pragma unroll
                    for (int e = 0; e < 8; ++e) a += qv[8 * j + e] * (float)k8[e];
                }
                s[t] = a;
            }
#pragma unroll
            for (int t = 0; t < 8; ++t) s[t] += __shfl_xor(s[t], 8, 64);

            float m = s[0];
#pragma unroll
            for (int t = 1; t < 8; ++t) m = fmaxf(m, s[t]);
            float pr[8], psum = 0.f;
#pragma unroll
            for (int t = 0; t < 8; ++t) {
                pr[t] = exp2f((s[t] - m) * 1.44269504088896f);
                psum += pr[t];
            }
            float inv = 1.0f / psum;

            float o[32];
#pragma unroll
            for (int e = 0; e < 32; ++e) o[e] = 0.f;
#pragma unroll
            for (int t = 0; t < 8; ++t) {
                float pt = pr[t] * inv;
                const bf16_t* vp = base + 1024 + t * 64 + d0;
#pragma unroll
                for (int j = 0; j < 4; ++j) {
                    bf16x8 v8 = *(const bf16x8*)(vp + 8 * j);
#pragma unroll
                    for (int e = 0; e < 8; ++e) o[8 * j + e] += pt * (float)v8[e];
                }
            }

            // ---- o -> LDS fp32 (all ex reads done first) -------------------
            __builtin_amdgcn_s_barrier();
            MEMFENCE;
            {
                int obase = tl * OSTR + h * 64 + d0;
#pragma unroll
                for (int j = 0; j < 8; ++j) {
                    f32x4 o4 = {o[4*j], o[4*j+1], o[4*j+2], o[4*j+3]};
                    *(f32x4*)(ob + obase + 4 * j) = o4;
                }
            }
            asm volatile("s_waitcnt lgkmcnt(0)" ::: "memory");
            __builtin_amdgcn_s_barrier();
            MEMFENCE;
        }

        // ---- lane-contiguous copy LDS -> out (nt, full 64B lines) ----------
#pragma unroll
        for (int it = 0; it < 8; ++it) {
            int f   = it * 256 + tid;             // 0..2047 (float4 units)
            int row = f >> 7;                     // 16 rows x 128 float4
            int col = (f & 127) * 4;
            f32x4 v4 = *(const f32x4*)(ob + row * OSTR + col);
            __builtin_nontemporal_store(
                v4, (f32x4*)(out + (tok0 + mi * 16 + row) * DM + col));
        }
        // ob reads done before next pass's exchange overwrites the region
        __builtin_amdgcn_s_barrier();
        MEMFENCE;
    }
}

// ---------------------------------------------------------------------------
extern "C" void kernel_launch(void* const* d_in, const int* in_sizes, int n_in,
                              void* d_out, int out_size, void* d_ws, size_t ws_size,
                              hipStream_t stream) {
    (void)d_ws; (void)ws_size; (void)n_in; (void)out_size;
    const float* x  = (const float*)d_in[0];
    const float* Wq = (const float*)d_in[1];
    const float* Wk = (const float*)d_in[2];
    const float* Wv = (const float*)d_in[3];
    float* out = (float*)d_out;

    int ntok = in_sizes[0] / DM;                  // 65536
    prep_w2<<<384, 256, 0, stream>>>(Wq, Wk, Wv);
    size_t lds = 81920;                           // A 32K + ring 48K (2 blk/CU)
    fused_mha<<<ntok / TM, 256, lds, stream>>>(x, out);
}

// Round 16
// 204.219 us; speedup vs baseline: 1.3489x; 1.1110x over previous
//
#include <hip/hip_runtime.h>
#include <hip/hip_bf16.h>

typedef __bf16 bf16_t;
typedef __bf16 bf16x8 __attribute__((ext_vector_type(8)));
typedef float  f32x4  __attribute__((ext_vector_type(4)));

#define DM    512
#define NQKV  1536
#define NTOK  65536
#define TM    64          // tokens per block (4 x 16 m-frags)
#define EXSTR 1544        // exchange LDS row stride (elems): 1536 + 8 pad

// Fragment-major repacked weights ("flatmm shuffle", R6/R11 mapping):
// for wave w (0..7), K-step s (0..15), ni (0..11), lane l (0..63), e (0..7):
//   ELEM offset = (((w*16+s)*12+ni)*64 + l)*8 + e
//   n = w*192+ni*16+(l&15);  k = s*32+(l>>4)*8+e
// Per-wave slice = 98304 elems; half-step h (s=h>>1, half=h&1) = 3072 elems.
__device__ __align__(16) bf16_t g_wt2[(size_t)NQKV * DM];

#define MEMFENCE asm volatile("" ::: "memory")

typedef const void __attribute__((address_space(1)))* gas_t;
typedef void       __attribute__((address_space(3)))* sas_t;
__device__ __forceinline__ void gl_lds16(const void* g, void* s) {
    // async global->LDS, 16B/lane; LDS dest = wave-uniform base + lane*16
    __builtin_amdgcn_global_load_lds((gas_t)g, (sas_t)s, 16, 0, 0);
}

// ---------------------------------------------------------------------------
// Kernel 1: scatter W_q|W_k|W_v (fp32 [k][n]) -> g_wt2 fragment-major bf16
// ---------------------------------------------------------------------------
__global__ void prep_w2(const float* __restrict__ Wq,
                        const float* __restrict__ Wk,
                        const float* __restrict__ Wv) {
    int flat = blockIdx.x * 256 + threadIdx.x;   // 0..98303 (one bf16x8 each)
    int l  = flat & 63;
    int kg = l >> 4, lr = l & 15;
    int t2 = flat >> 6;
    int ni = t2 % 12;
    int t3 = t2 / 12;
    int s  = t3 & 15, w = t3 >> 4;
    int n  = w * 192 + ni * 16 + lr;             // 0..1535
    int k0 = s * 32 + kg * 8;
    int mat = n >> 9, nn = n & 511;
    const float* W = (mat == 0) ? Wq : ((mat == 1) ? Wk : Wv);
    bf16x8 v;
#pragma unroll
    for (int e = 0; e < 8; ++e) v[e] = (bf16_t)W[(k0 + e) * DM + nn];
    *(bf16x8*)(g_wt2 + (size_t)flat * 8) = v;
}

// ---------------------------------------------------------------------------
// Kernel 2: fused QKV projection + cross-head attention.
// 64 tokens/block, 8 waves, 1024 blocks (= exactly 4 full CU generations).
// R16 = R11 structure with TM 48->64: B re-read traffic 2.05 -> 1.54 GB.
// LDS (163840 B = 160 KiB exactly, 1 block/CU):
//   [0,64K)   A tile [64][512] bf16, 16B-chunk XOR swizzle
//   [64K,160K) B ring: 8 waves x 2 slots x 6144 B
//   after K-loop: ex[32][EXSTR] bf16 (98816 B) overlays from 0, two passes
// K-loop: 32 half-steps, counted vmcnt(6) (R10 mechanism, unchanged).
// ---------------------------------------------------------------------------
__global__ __launch_bounds__(512, 1) void fused_mha(
    const float* __restrict__ x, float* __restrict__ out) {
    extern __shared__ char sm[];        // 163840 B

    const int tid = threadIdx.x;
    const int l   = tid & 63, w = tid >> 6;       // lane, wave 0..7
    const int lr  = l & 15,  kg = l >> 4;
    const size_t tok0 = (size_t)blockIdx.x * TM;

    // ---- stage x tile: fp32 global -> bf16 LDS, 16B-chunk XOR swizzle ------
#pragma unroll
    for (int p = 0; p < 8; ++p) {
        int flat = p * 512 + tid;                 // 0..4095
        int r = flat >> 6, c = flat & 63;         // row 0..63, chunk 0..63
        const float* xp = x + (tok0 + r) * DM + c * 8;
        float4 f0 = *(const float4*)(xp);
        float4 f1 = *(const float4*)(xp + 4);
        bf16x8 v;
        v[0] = (bf16_t)f0.x; v[1] = (bf16_t)f0.y;
        v[2] = (bf16_t)f0.z; v[3] = (bf16_t)f0.w;
        v[4] = (bf16_t)f1.x; v[5] = (bf16_t)f1.y;
        v[6] = (bf16_t)f1.z; v[7] = (bf16_t)f1.w;
        *(bf16x8*)(sm + r * 1024 + ((c ^ (r & 7)) << 4)) = v;
    }

    // ---- B ring: 2 slots x 6144 B per wave at sm+65536 --------------------
    const bf16_t* gwB = g_wt2 + (size_t)w * 98304 + l * 8;    // elem offsets
    char* ringW = sm + 65536 + w * 12288;                      // wave-uniform

#define ISSUE6(h_)                                                            \
    do {                                                                      \
        _Pragma("unroll")                                                     \
        for (int ii = 0; ii < 6; ++ii)                                        \
            gl_lds16(gwB + (size_t)(h_) * 3072 + ii * 512,                    \
                     ringW + ((h_) & 1) * 6144 + ii * 1024);                  \
    } while (0)
#define WAITVM(n_) asm volatile("s_waitcnt vmcnt(" #n_ ")" ::: "memory")

    // prologue: half-steps 0,1 in flight before the staging barrier
    ISSUE6(0); ISSUE6(1);
    asm volatile("s_waitcnt lgkmcnt(0)" ::: "memory");  // x ds_writes drained
    __builtin_amdgcn_s_barrier();
    MEMFENCE;

    // ---- barrier-free K-loop: 32 half-steps, fully unrolled ----------------
    f32x4 acc[4][12];
#pragma unroll
    for (int a = 0; a < 4; ++a)
#pragma unroll
        for (int b = 0; b < 12; ++b) acc[a][b] = (f32x4){0.f, 0.f, 0.f, 0.f};

    const int sx = (lr & 7) << 4;               // A-read swizzle term
    bf16x8 af[4];

#define HSTEP(h_, vm_)                                                        \
    do {                                                                      \
        WAITVM(vm_);              /* slot h_'s 6 stage-loads retired */       \
        bf16x8 bf_[6];                                                        \
        _Pragma("unroll")                                                     \
        for (int ni = 0; ni < 6; ++ni)                                        \
            bf_[ni] = *(const bf16x8*)(ringW + ((h_) & 1) * 6144 +            \
                                       ni * 1024 + l * 16);                   \
        if (((h_) & 1) == 0) {                                                \
            _Pragma("unroll")                                                 \
            for (int mi = 0; mi < 4; ++mi)                                    \
                af[mi] = *(const bf16x8*)(sm + (mi * 16 + lr) * 1024 +        \
                                          ((((h_) >> 1) * 64 + kg * 16) ^ sx)); \
        }                                                                     \
        asm volatile("s_waitcnt lgkmcnt(0)" ::: "memory");                    \
        __builtin_amdgcn_sched_barrier(0);      /* rule #18 */                \
        if ((h_) + 2 < 32) ISSUE6((h_) + 2);    /* refill freed slot */       \
        __builtin_amdgcn_s_setprio(1);                                        \
        _Pragma("unroll")                                                     \
        for (int mi = 0; mi < 4; ++mi)                                        \
        _Pragma("unroll")                                                     \
        for (int ni = 0; ni < 6; ++ni)                                        \
            acc[mi][((h_) & 1) * 6 + ni] =                                    \
                __builtin_amdgcn_mfma_f32_16x16x32_bf16(                      \
                    af[mi], bf_[ni], acc[mi][((h_) & 1) * 6 + ni], 0, 0, 0);  \
        __builtin_amdgcn_s_setprio(0);                                        \
    } while (0)

    HSTEP( 0, 6); HSTEP( 1, 6); HSTEP( 2, 6); HSTEP( 3, 6);
    HSTEP( 4, 6); HSTEP( 5, 6); HSTEP( 6, 6); HSTEP( 7, 6);
    HSTEP( 8, 6); HSTEP( 9, 6); HSTEP(10, 6); HSTEP(11, 6);
    HSTEP(12, 6); HSTEP(13, 6); HSTEP(14, 6); HSTEP(15, 6);
    HSTEP(16, 6); HSTEP(17, 6); HSTEP(18, 6); HSTEP(19, 6);
    HSTEP(20, 6); HSTEP(21, 6); HSTEP(22, 6); HSTEP(23, 6);
    HSTEP(24, 6); HSTEP(25, 6); HSTEP(26, 6); HSTEP(27, 6);
    HSTEP(28, 6); HSTEP(29, 6); HSTEP(30, 6); HSTEP(31, 0);
#undef HSTEP
#undef ISSUE6
#undef WAITVM

    // ---- A + ring dead; full drain + sync before ex overlays ---------------
    asm volatile("s_waitcnt vmcnt(0) lgkmcnt(0)" ::: "memory");
    __builtin_amdgcn_s_barrier();
    MEMFENCE;

    // ---- two passes of 32 tokens: exchange -> attention -> store -----------
    bf16_t* ex = (bf16_t*)sm;
#pragma unroll
    for (int p = 0; p < 2; ++p) {
        // exchange: acc[2p], acc[2p+1] -> ex[32][EXSTR] (row = token-in-pass)
#pragma unroll
        for (int mm = 0; mm < 2; ++mm)
#pragma unroll
            for (int ni = 0; ni < 12; ++ni) {
                int col = w * 192 + ni * 16 + lr;
#pragma unroll
                for (int i = 0; i < 4; ++i) {
                    int tl = mm * 16 + kg * 4 + i;    // 0..31
                    ex[tl * EXSTR + col] = (bf16_t)acc[p * 2 + mm][ni][i];
                }
            }
        asm volatile("s_waitcnt lgkmcnt(0)" ::: "memory");
        __builtin_amdgcn_s_barrier();
        MEMFENCE;

        // attention: 16 threads per token, 32 tokens (= 512 threads exactly)
        {
            const int tok = tid >> 4, tj = tid & 15, h = tj & 7, d0 = (tj >> 3) << 5;
            const bf16_t* base = ex + tok * EXSTR;

            float qv[32];
            {
                const bf16_t* qp = base + h * 64 + d0;
#pragma unroll
                for (int j = 0; j < 4; ++j) {
                    bf16x8 q8 = *(const bf16x8*)(qp + 8 * j);
#pragma unroll
                    for (int e = 0; e < 8; ++e) qv[8 * j + e] = (float)q8[e];
                }
            }

            float s[8];
#pragma unroll
            for (int t = 0; t < 8; ++t) {
                const bf16_t* kp = base + 512 + t * 64 + d0;
                float a = 0.f;
#pragma unroll
                for (int j = 0; j < 4; ++j) {
                    bf16x8 k8 = *(const bf16x8*)(kp + 8 * j);
#pragma unroll
                    for (int e = 0; e < 8; ++e) a += qv[8 * j + e] * (float)k8[e];
                }
                s[t] = a;
            }
            // combine two d-halves (partner lane tid^8: same token, same h)
#pragma unroll
            for (int t = 0; t < 8; ++t) s[t] += __shfl_xor(s[t], 8, 64);

            float m = s[0];
#pragma unroll
            for (int t = 1; t < 8; ++t) m = fmaxf(m, s[t]);
            float pr[8], psum = 0.f;
#pragma unroll
            for (int t = 0; t < 8; ++t) {
                pr[t] = exp2f((s[t] - m) * 1.44269504088896f);
                psum += pr[t];
            }
            float inv = 1.0f / psum;

            float o[32];
#pragma unroll
            for (int e = 0; e < 32; ++e) o[e] = 0.f;
#pragma unroll
            for (int t = 0; t < 8; ++t) {
                float pt = pr[t] * inv;
                const bf16_t* vp = base + 1024 + t * 64 + d0;
#pragma unroll
                for (int j = 0; j < 4; ++j) {
                    bf16x8 v8 = *(const bf16x8*)(vp + 8 * j);
#pragma unroll
                    for (int e = 0; e < 8; ++e) o[8 * j + e] += pt * (float)v8[e];
                }
            }

            float* op = out + (tok0 + p * 32 + tok) * DM + h * 64 + d0;
#pragma unroll
            for (int j = 0; j < 8; ++j) {
                float4 o4 = {o[4 * j], o[4 * j + 1], o[4 * j + 2], o[4 * j + 3]};
                *(float4*)(op + 4 * j) = o4;
            }
        }
        if (p == 0) {                  // ex reads done before pass-2 overwrite
            __builtin_amdgcn_s_barrier();
            MEMFENCE;
        }
    }
}

// ---------------------------------------------------------------------------
extern "C" void kernel_launch(void* const* d_in, const int* in_sizes, int n_in,
                              void* d_out, int out_size, void* d_ws, size_t ws_size,
                              hipStream_t stream) {
    (void)d_ws; (void)ws_size; (void)n_in; (void)out_size;
    const float* x  = (const float*)d_in[0];
    const float* Wq = (const float*)d_in[1];
    const float* Wk = (const float*)d_in[2];
    const float* Wv = (const float*)d_in[3];
    float* out = (float*)d_out;

    int ntok = in_sizes[0] / DM;                  // 65536
    prep_w2<<<384, 256, 0, stream>>>(Wq, Wk, Wv);
    size_t lds = 163840;                          // A 64K + ring 96K (160 KiB)
    fused_mha<<<ntok / TM, 512, lds, stream>>>(x, out);
}

// Round 17
// 203.954 us; speedup vs baseline: 1.3507x; 1.0013x over previous
//
#include <hip/hip_runtime.h>
#include <hip/hip_bf16.h>

typedef __bf16 bf16_t;
typedef __bf16 bf16x8 __attribute__((ext_vector_type(8)));
typedef float  f32x4  __attribute__((ext_vector_type(4)));

#define DM    512
#define NQKV  1536
#define NTOK  65536
#define TM    48          // tokens per block (3 x 16 m-frags)
#define QSTR  1544        // qkv LDS row stride (elems): 1536 + 8 pad

// Fragment-major repacked weights ("flatmm shuffle"): for wave w (0..7),
// K-step s (0..15), ni (0..11), lane l (0..63), elem e (0..7):
//   ELEM offset = (((w*16+s)*12+ni)*64 + l)*8 + e
//   n = w*192+ni*16+(l&15);  k = s*32+(l>>4)*8+e
// Half-step h (s=h>>1, half=h&1): 6 frags at ELEM offset w*98304 + h*3072
// (= 6144 BYTES per half-step: 6 frags x 64 lanes x 16 B).
__device__ __align__(16) bf16_t g_wt2[(size_t)NQKV * DM];

#define MEMFENCE asm volatile("" ::: "memory")

typedef const void __attribute__((address_space(1)))* gas_t;
typedef void       __attribute__((address_space(3)))* sas_t;
__device__ __forceinline__ void gl_lds16(const void* g, void* s) {
    // async global->LDS, 16B/lane; LDS dest = wave-uniform base + lane*16
    __builtin_amdgcn_global_load_lds((gas_t)g, (sas_t)s, 16, 0, 0);
}

// ---------------------------------------------------------------------------
// Kernel 1: scatter W_q|W_k|W_v (fp32 [k][n]) -> g_wt2 fragment-major bf16
// ---------------------------------------------------------------------------
__global__ void prep_w2(const float* __restrict__ Wq,
                        const float* __restrict__ Wk,
                        const float* __restrict__ Wv) {
    int flat = blockIdx.x * 256 + threadIdx.x;   // 0..98303 (one bf16x8 each)
    int l  = flat & 63;
    int kg = l >> 4, lr = l & 15;
    int t2 = flat >> 6;
    int ni = t2 % 12;
    int t3 = t2 / 12;
    int s  = t3 & 15, w = t3 >> 4;
    int n  = w * 192 + ni * 16 + lr;             // 0..1535
    int k0 = s * 32 + kg * 8;
    int mat = n >> 9, nn = n & 511;
    const float* W = (mat == 0) ? Wq : ((mat == 1) ? Wk : Wv);
    bf16x8 v;
#pragma unroll
    for (int e = 0; e < 8; ++e) v[e] = (bf16_t)W[(k0 + e) * DM + nn];
    *(bf16x8*)(g_wt2 + (size_t)flat * 8) = v;
}

// ---------------------------------------------------------------------------
// Kernel 2: fused QKV projection + cross-head attention (R11 structure).
// 48 tokens/block, 8 waves, 1366 blocks. A (x tile) in LDS [0,48K); B
// streamed through a wave-private 2-slot LDS ring (slot 6144 B) at
// [48K,144K+3K) via global_load_lds + counted vmcnt. Barrier-free K-loop.
// R17 = R11 + NON-TEMPORAL x loads (R14-verified: nt loads keep the 1.5 MB
// weight set L2-resident; out stores stay cached -- nt stores 4x-amplified).
// After K-loop: qkv [48][QSTR] (148224 B) overlays from 0 (drain+barrier).
// ---------------------------------------------------------------------------
__global__ __launch_bounds__(512, 1) void fused_mha(
    const float* __restrict__ x, float* __restrict__ out) {
    extern __shared__ char sm[];        // 148224 B

    const int tid = threadIdx.x;
    const int l   = tid & 63, w = tid >> 6;
    const int lr  = l & 15,  kg = l >> 4;
    const size_t tok0 = (size_t)blockIdx.x * TM;
    const int ntb = (int)(((size_t)NTOK - tok0) < TM ? (NTOK - tok0) : TM);

    // ---- stage x tile: fp32 global (nt) -> bf16 LDS, 16B-chunk XOR swizzle -
    {
        const int rbase = tid >> 5;               // 0..15
        const int cj    = tid & 31;
#pragma unroll
        for (int p = 0; p < 3; ++p) {
            int r = p * 16 + rbase;               // 0..47
            int r7 = r & 7;
            if (r < ntb) {
                const float* xp = x + (tok0 + r) * DM;
#pragma unroll
                for (int jj = 0; jj < 2; ++jj) {
                    int c = cj + jj * 32;         // chunk 0..63 (8 bf16 each)
                    const f32x4* gp = (const f32x4*)(xp + c * 8);
                    f32x4 f0 = __builtin_nontemporal_load(gp);
                    f32x4 f1 = __builtin_nontemporal_load(gp + 1);
                    bf16x8 v;
                    v[0] = (bf16_t)f0.x; v[1] = (bf16_t)f0.y;
                    v[2] = (bf16_t)f0.z; v[3] = (bf16_t)f0.w;
                    v[4] = (bf16_t)f1.x; v[5] = (bf16_t)f1.y;
                    v[6] = (bf16_t)f1.z; v[7] = (bf16_t)f1.w;
                    *(bf16x8*)(sm + r * 1024 + ((c ^ r7) << 4)) = v;
                }
            } else {                               // remainder block: zero rows
                bf16x8 z;
#pragma unroll
                for (int e = 0; e < 8; ++e) z[e] = (bf16_t)0.f;
#pragma unroll
                for (int jj = 0; jj < 2; ++jj) {
                    int c = cj + jj * 32;
                    *(bf16x8*)(sm + r * 1024 + ((c ^ r7) << 4)) = z;
                }
            }
        }
    }

    // ---- B ring: 2 slots x 6144 B per wave at sm+49152 --------------------
    const bf16_t* gwB = g_wt2 + (size_t)w * 98304 + l * 8;   // elem offsets
    char* ringW = sm + 49152 + w * 12288;                     // wave-uniform

#define ISSUE6(h_)                                                            \
    do {                                                                      \
        _Pragma("unroll")                                                     \
        for (int ii = 0; ii < 6; ++ii)                                        \
            gl_lds16(gwB + (size_t)(h_) * 3072 + ii * 512,                    \
                     ringW + ((h_) & 1) * 6144 + ii * 1024);                  \
    } while (0)
#define WAITVM(n_) asm volatile("s_waitcnt vmcnt(" #n_ ")" ::: "memory")

    // prologue: half-steps 0,1 in flight before the staging barrier
    ISSUE6(0); ISSUE6(1);
    asm volatile("s_waitcnt lgkmcnt(0)" ::: "memory");  // x ds_writes drained
    __builtin_amdgcn_s_barrier();
    MEMFENCE;

    // ---- barrier-free K-loop: 32 half-steps, fully unrolled ----------------
    f32x4 acc[3][12];
#pragma unroll
    for (int a = 0; a < 3; ++a)
#pragma unroll
        for (int b = 0; b < 12; ++b) acc[a][b] = (f32x4){0.f, 0.f, 0.f, 0.f};

    const int sx = (lr & 7) << 4;               // A-read swizzle term
    bf16x8 af[3];

#define HSTEP(h_, vm_)                                                        \
    do {                                                                      \
        WAITVM(vm_);              /* slot h_'s 6 stage-loads retired */       \
        bf16x8 bf_[6];                                                        \
        _Pragma("unroll")                                                     \
        for (int ni = 0; ni < 6; ++ni)                                        \
            bf_[ni] = *(const bf16x8*)(ringW + ((h_) & 1) * 6144 +            \
                                       ni * 1024 + l * 16);                   \
        if (((h_) & 1) == 0) {                                                \
            _Pragma("unroll")                                                 \
            for (int mi = 0; mi < 3; ++mi)                                    \
                af[mi] = *(const bf16x8*)(sm + (mi * 16 + lr) * 1024 +        \
                                          ((((h_) >> 1) * 64 + kg * 16) ^ sx)); \
        }                                                                     \
        asm volatile("s_waitcnt lgkmcnt(0)" ::: "memory");                    \
        __builtin_amdgcn_sched_barrier(0);      /* rule #18 */                \
        if ((h_) + 2 < 32) ISSUE6((h_) + 2);    /* refill freed slot */       \
        __builtin_amdgcn_s_setprio(1);                                        \
        _Pragma("unroll")                                                     \
        for (int mi = 0; mi < 3; ++mi)                                        \
        _Pragma("unroll")                                                     \
        for (int ni = 0; ni < 6; ++ni)                                        \
            acc[mi][((h_) & 1) * 6 + ni] =                                    \
                __builtin_amdgcn_mfma_f32_16x16x32_bf16(                      \
                    af[mi], bf_[ni], acc[mi][((h_) & 1) * 6 + ni], 0, 0, 0);  \
        __builtin_amdgcn_s_setprio(0);                                        \
    } while (0)

    HSTEP( 0, 6); HSTEP( 1, 6); HSTEP( 2, 6); HSTEP( 3, 6);
    HSTEP( 4, 6); HSTEP( 5, 6); HSTEP( 6, 6); HSTEP( 7, 6);
    HSTEP( 8, 6); HSTEP( 9, 6); HSTEP(10, 6); HSTEP(11, 6);
    HSTEP(12, 6); HSTEP(13, 6); HSTEP(14, 6); HSTEP(15, 6);
    HSTEP(16, 6); HSTEP(17, 6); HSTEP(18, 6); HSTEP(19, 6);
    HSTEP(20, 6); HSTEP(21, 6); HSTEP(22, 6); HSTEP(23, 6);
    HSTEP(24, 6); HSTEP(25, 6); HSTEP(26, 6); HSTEP(27, 6);
    HSTEP(28, 6); HSTEP(29, 6); HSTEP(30, 6); HSTEP(31, 0);
#undef HSTEP
#undef ISSUE6
#undef WAITVM

    // ---- A + ring dead; full drain + sync before qkv overlays --------------
    asm volatile("s_waitcnt vmcnt(0) lgkmcnt(0)" ::: "memory");
    __builtin_amdgcn_s_barrier();
    MEMFENCE;

    // ---- epilogue: acc -> qkv LDS [48][QSTR] (row = token, col = n) --------
    bf16_t* qkv = (bf16_t*)sm;
#pragma unroll
    for (int mi = 0; mi < 3; ++mi)
#pragma unroll
        for (int ni = 0; ni < 12; ++ni) {
            int col = w * 192 + ni * 16 + lr;
#pragma unroll
            for (int i = 0; i < 4; ++i) {
                int token = mi * 16 + kg * 4 + i;
                qkv[token * QSTR + col] = (bf16_t)acc[mi][ni][i];
            }
        }
    asm volatile("s_waitcnt lgkmcnt(0)" ::: "memory");
    __builtin_amdgcn_s_barrier();
    MEMFENCE;

    // ---- attention: 16 threads/token, two passes (0..31, 32..47) ----------
#pragma unroll
    for (int p = 0; p < 2; ++p) {
        const int tok = p * 32 + (tid >> 4);
        if (tok < ntb) {
            const int tj = tid & 15, h = tj & 7, d0 = (tj >> 3) << 5;
            const bf16_t* base = qkv + tok * QSTR;

            float qv[32];
            {
                const bf16_t* qp = base + h * 64 + d0;
#pragma unroll
                for (int j = 0; j < 4; ++j) {
                    bf16x8 q8 = *(const bf16x8*)(qp + 8 * j);
#pragma unroll
                    for (int e = 0; e < 8; ++e) qv[8 * j + e] = (float)q8[e];
                }
            }

            float s[8];
#pragma unroll
            for (int t = 0; t < 8; ++t) {
                const bf16_t* kp = base + 512 + t * 64 + d0;
                float a = 0.f;
#pragma unroll
                for (int j = 0; j < 4; ++j) {
                    bf16x8 k8 = *(const bf16x8*)(kp + 8 * j);
#pragma unroll
                    for (int e = 0; e < 8; ++e) a += qv[8 * j + e] * (float)k8[e];
                }
                s[t] = a;
            }
            // combine two d-halves (partner lane tid^8: same tok, same h)
#pragma unroll
            for (int t = 0; t < 8; ++t) s[t] += __shfl_xor(s[t], 8, 64);

            float m = s[0];
#pragma unroll
            for (int t = 1; t < 8; ++t) m = fmaxf(m, s[t]);
            float pr[8], psum = 0.f;
#pragma unroll
            for (int t = 0; t < 8; ++t) {
                pr[t] = exp2f((s[t] - m) * 1.44269504088896f);
                psum += pr[t];
            }
            float inv = 1.0f / psum;

            float o[32];
#pragma unroll
            for (int e = 0; e < 32; ++e) o[e] = 0.f;
#pragma unroll
            for (int t = 0; t < 8; ++t) {
                float pt = pr[t] * inv;
                const bf16_t* vp = base + 1024 + t * 64 + d0;
#pragma unroll
                for (int j = 0; j < 4; ++j) {
                    bf16x8 v8 = *(const bf16x8*)(vp + 8 * j);
#pragma unroll
                    for (int e = 0; e < 8; ++e) o[8 * j + e] += pt * (float)v8[e];
                }
            }

            float* op = out + (tok0 + tok) * DM + h * 64 + d0;
#pragma unroll
            for (int j = 0; j < 8; ++j) {
                float4 o4 = {o[4 * j], o[4 * j + 1], o[4 * j + 2], o[4 * j + 3]};
                *(float4*)(op + 4 * j) = o4;
            }
        }
    }
}

// ---------------------------------------------------------------------------
extern "C" void kernel_launch(void* const* d_in, const int* in_sizes, int n_in,
                              void* d_out, int out_size, void* d_ws, size_t ws_size,
                              hipStream_t stream) {
    (void)d_ws; (void)ws_size; (void)n_in; (void)out_size;
    const float* x  = (const float*)d_in[0];
    const float* Wq = (const float*)d_in[1];
    const float* Wk = (const float*)d_in[2];
    const float* Wv = (const float*)d_in[3];
    float* out = (float*)d_out;

    int ntok = in_sizes[0] / DM;                   // 65536
    int grid = (ntok + TM - 1) / TM;               // 1366 (last block: 16 tokens)
    prep_w2<<<384, 256, 0, stream>>>(Wq, Wk, Wv);
    size_t lds = (size_t)TM * QSTR * sizeof(bf16_t);   // 148224 B
    fused_mha<<<grid, 512, lds, stream>>>(x, out);
}